// Round 1
// baseline (69.219 us; speedup 1.0000x reference)
//
#include <hip/hip_runtime.h>
#include <hip/hip_bf16.h>
#include <math.h>

#define B_ 4
#define N_ 256
#define M_ 512
#define E_ 256
#define H_ 64

typedef __attribute__((ext_vector_type(8))) short bf16x8;
typedef __attribute__((ext_vector_type(4))) float f32x4;

// tanh-approx gelu: gelu(x) = x * E/(1+E), E = exp2(k1*x + k2*x^3)
// k1 = 2*sqrt(2/pi)*log2(e) = 2.3022081, k2 = k1*0.044715 = 0.1029432
__device__ __forceinline__ float gelu_t(float x) {
    float u = x * fmaf(0.1029432f, x * x, 2.3022081f);
    u = fminf(u, 80.0f);
    float E = exp2f(u);
    return x * E * __builtin_amdgcn_rcpf(1.0f + E);
}

// exact (erf) gelu for the FiLM generator (cheap, most-amplified path)
__device__ __forceinline__ float gelu_e(float x) {
    return 0.5f * x * (1.0f + erff(x * 0.70710678118654752f));
}

// fp32 -> bf16 bits, round-to-nearest-even
__device__ __forceinline__ short f2bf(float f) {
    unsigned u = __float_as_uint(f);
    unsigned r = (u + 0x7FFFu + ((u >> 16) & 1u)) >> 16;
    return (short)r;
}

__global__ void film_kmax_kernel(const float* __restrict__ z,
                                 const float* __restrict__ mu,
                                 unsigned* __restrict__ wsmax) {
    const int total = B_ * N_ * M_;
    int idx = blockIdx.x * blockDim.x + threadIdx.x;
    float mx = 0.0f;
    for (int i = idx; i < total; i += gridDim.x * blockDim.x) {
        int bn = i >> 9;          // / M_
        int m  = i & (M_ - 1);
        float dz0 = z[2 * m]     - mu[2 * bn];
        float dz1 = z[2 * m + 1] - mu[2 * bn + 1];
        float d2 = dz0 * dz0 + dz1 * dz1;
        mx = fmaxf(mx, d2);
    }
    #pragma unroll
    for (int off = 32; off; off >>= 1) mx = fmaxf(mx, __shfl_xor(mx, off, 64));
    __shared__ float sred[4];
    int lane = threadIdx.x & 63, wid = threadIdx.x >> 6;
    if (lane == 0) sred[wid] = mx;
    __syncthreads();
    if (threadIdx.x == 0) {
        float m2 = fmaxf(fmaxf(sred[0], sred[1]), fmaxf(sred[2], sred[3]));
        atomicMax(wsmax, __float_as_uint(m2));
    }
}

__global__ __launch_bounds__(256, 3) void film_main_kernel(
    const float* __restrict__ z, const float* __restrict__ mu,
    const float* __restrict__ emb,
    const float* __restrict__ fg_w1, const float* __restrict__ fg_b1,
    const float* __restrict__ fg_w2, const float* __restrict__ fg_b2,
    const float* __restrict__ kn_w0, const float* __restrict__ kn_b0,
    const float* __restrict__ kn_w2, const float* __restrict__ kn_b2,
    const float* __restrict__ kn_w4, const float* __restrict__ kn_b4,
    const unsigned* __restrict__ wsmax,
    float* __restrict__ out) {
    __shared__ float s_emb[E_];
    __shared__ float s_part[256];
    __shared__ float s_h[H_];
    __shared__ float s_scale[H_], s_shift[H_];
    __shared__ float s_A1[H_], s_A0[H_];

    const int t = threadIdx.x;
    const int bn = blockIdx.x;   // b*N + n

    // ---- FiLM generator for this (b,n) ----
    s_emb[t] = emb[bn * E_ + t];
    __syncthreads();
    {
        int g = t & 63, q = t >> 6;
        const float* w1r = fg_w1 + g * E_ + q * 64;
        const float* er  = s_emb + q * 64;
        float acc = 0.0f;
        #pragma unroll
        for (int e = 0; e < 64; e++) acc = fmaf(w1r[e], er[e], acc);
        s_part[t] = acc;
    }
    __syncthreads();
    if (t < H_) {
        float hv = s_part[t] + s_part[64 + t] + s_part[128 + t] + s_part[192 + t] + fg_b1[t];
        s_h[t] = gelu_e(hv);
    }
    __syncthreads();
    if (t < 2 * H_) {
        const float* w2r = fg_w2 + t * H_;
        float acc = fg_b2[t];
        #pragma unroll
        for (int h = 0; h < H_; h++) acc = fmaf(w2r[h], s_h[h], acc);
        if (t < H_) s_scale[t] = acc; else s_shift[t - H_] = acc;
    }
    __syncthreads();
    if (t < H_) {
        float sc = s_scale[t];
        s_A1[t] = sc * kn_w0[t];                      // coeff of nd
        s_A0[t] = fmaf(sc, kn_b0[t], s_shift[t]);     // constant term
    }
    __syncthreads();

    // ---- per-wave invariants ----
    const int lane = t & 63;
    const int wid  = t >> 6;
    const int kg   = lane >> 4;   // k-slot group 0..3
    const int cl   = lane & 15;   // row (A) / col (B,C)

    float maxd2 = __uint_as_float(*wsmax);
    float invd  = __builtin_amdgcn_rcpf(sqrtf(maxd2) + 1e-8f);
    float mu0 = mu[bn * 2], mu1 = mu[bn * 2 + 1];

    float A1r[16], A0r[16];
    #pragma unroll
    for (int c = 0; c < 2; c++)
        #pragma unroll
        for (int j = 0; j < 8; j++) {
            int h = c * 32 + kg * 8 + j;
            A1r[c * 8 + j] = s_A1[h];
            A0r[c * 8 + j] = s_A0[h];
        }

    bf16x8 bfr[2][4];   // B fragments: w2[col][h], same h-slot map as A
    #pragma unroll
    for (int c = 0; c < 2; c++)
        #pragma unroll
        for (int ct = 0; ct < 4; ct++) {
            int col = ct * 16 + cl;
            const float* wr = kn_w2 + col * H_ + c * 32 + kg * 8;
            bf16x8 v;
            #pragma unroll
            for (int j = 0; j < 8; j++) v[j] = f2bf(wr[j]);
            bfr[c][ct] = v;
        }

    float scE[4], shE[4], w4E[4], b2E[4];
    #pragma unroll
    for (int ct = 0; ct < 4; ct++) {
        int col = ct * 16 + cl;
        scE[ct] = s_scale[col];
        shE[ct] = s_shift[col];
        w4E[ct] = kn_w4[col];
        b2E[ct] = kn_b2[col];
    }
    float b4v = kn_b4[0];
    float* outr = out + bn * M_;

    // ---- main loop: 8 tiles of 16 points per wave ----
    #pragma unroll 1
    for (int tile = 0; tile < 8; ++tile) {
        int mb = wid * 128 + tile * 16;
        int m  = mb + cl;
        float dz0 = z[2 * m] - mu0, dz1 = z[2 * m + 1] - mu1;
        float nd = sqrtf(dz0 * dz0 + dz1 * dz1) * invd;

        bf16x8 af[2];   // A fragments: x0[row=cl][h]
        #pragma unroll
        for (int c = 0; c < 2; c++) {
            bf16x8 v;
            #pragma unroll
            for (int j = 0; j < 8; j++) {
                float x0 = gelu_t(fmaf(nd, A1r[c * 8 + j], A0r[c * 8 + j]));
                v[j] = f2bf(x0);
            }
            af[c] = v;
        }

        f32x4 acc[4];
        #pragma unroll
        for (int ct = 0; ct < 4; ct++) {
            f32x4 a;
            a[0] = b2E[ct]; a[1] = b2E[ct]; a[2] = b2E[ct]; a[3] = b2E[ct];
            a = __builtin_amdgcn_mfma_f32_16x16x32_bf16(af[0], bfr[0][ct], a, 0, 0, 0);
            a = __builtin_amdgcn_mfma_f32_16x16x32_bf16(af[1], bfr[1][ct], a, 0, 0, 0);
            acc[ct] = a;
        }

        // epilogue: x2 = gelu(scale*x1+shift); y = sum_g x2*w4
        float y0 = 0, y1 = 0, y2 = 0, y3 = 0;
        #pragma unroll
        for (int ct = 0; ct < 4; ct++) {
            y0 = fmaf(gelu_t(fmaf(scE[ct], acc[ct][0], shE[ct])), w4E[ct], y0);
            y1 = fmaf(gelu_t(fmaf(scE[ct], acc[ct][1], shE[ct])), w4E[ct], y1);
            y2 = fmaf(gelu_t(fmaf(scE[ct], acc[ct][2], shE[ct])), w4E[ct], y2);
            y3 = fmaf(gelu_t(fmaf(scE[ct], acc[ct][3], shE[ct])), w4E[ct], y3);
        }
        // reduce over the 16 cols held by this 16-lane group
        #pragma unroll
        for (int off = 1; off < 16; off <<= 1) {
            y0 += __shfl_xor(y0, off, 16);
            y1 += __shfl_xor(y1, off, 16);
            y2 += __shfl_xor(y2, off, 16);
            y3 += __shfl_xor(y3, off, 16);
        }
        if (cl < 4) {
            float yv = (cl == 0) ? y0 : (cl == 1) ? y1 : (cl == 2) ? y2 : y3;
            yv += b4v;
            float E = exp2f(yv * 1.44269504f);
            float sg = E * __builtin_amdgcn_rcpf(1.0f + E);
            outr[mb + kg * 4 + cl] = sg;   // row = kg*4 + reg
        }
    }
}

extern "C" void kernel_launch(void* const* d_in, const int* in_sizes, int n_in,
                              void* d_out, int out_size, void* d_ws, size_t ws_size,
                              hipStream_t stream) {
    const float* z      = (const float*)d_in[0];
    const float* mu     = (const float*)d_in[1];
    const float* emb    = (const float*)d_in[2];
    const float* fg_w1  = (const float*)d_in[3];
    const float* fg_b1  = (const float*)d_in[4];
    const float* fg_w2  = (const float*)d_in[5];
    const float* fg_b2  = (const float*)d_in[6];
    const float* kn_w0  = (const float*)d_in[7];
    const float* kn_b0  = (const float*)d_in[8];
    const float* kn_w2  = (const float*)d_in[9];
    const float* kn_b2  = (const float*)d_in[10];
    const float* kn_w4  = (const float*)d_in[11];
    const float* kn_b4  = (const float*)d_in[12];
    float* out = (float*)d_out;
    unsigned* wsmax = (unsigned*)d_ws;

    hipMemsetAsync(d_ws, 0, 4, stream);
    film_kmax_kernel<<<512, 256, 0, stream>>>(z, mu, wsmax);
    film_main_kernel<<<B_ * N_, 256, 0, stream>>>(
        z, mu, emb, fg_w1, fg_b1, fg_w2, fg_b2,
        kn_w0, kn_b0, kn_w2, kn_b2, kn_w4, kn_b4, wsmax, out);
}